// Round 1
// baseline (1754.418 us; speedup 1.0000x reference)
//
#include <hip/hip_runtime.h>
#include <hip/hip_bf16.h>
#include <math.h>

#define BATCH 16384

typedef unsigned short u16;
typedef short bf16x8 __attribute__((ext_vector_type(8)));
typedef float f32x4 __attribute__((ext_vector_type(4)));
typedef u16 u16x8 __attribute__((ext_vector_type(8)));

__constant__ int PERMS_C[6][3] = {{0,1,2},{0,2,1},{1,0,2},{1,2,0},{2,0,1},{2,1,0}};

__device__ inline float bf2f(u16 u) {
    unsigned int x = ((unsigned int)u) << 16;
    float f; __builtin_memcpy(&f, &x, 4); return f;
}
__device__ inline u16 f2bf(float f) {
    __hip_bfloat16 h = __float2bfloat16(f);
    u16 u; __builtin_memcpy(&u, &h, 2); return u;
}
__device__ inline float gelu_exact(float x) {
    return 0.5f * x * (1.0f + erff(x * 0.70710678118654752f));
}

// ---------------------------------------------------------------------------
// prep: convert seq_embed to bf16, build transposed bf16 weight blocks,
// concatenated biases, zero states + loss accumulators.
// ---------------------------------------------------------------------------
__global__ __launch_bounds__(256) void prep_kernel(
    const float* __restrict__ seq,
    const float* __restrict__ pw1, const float* __restrict__ pw2,
    const float* __restrict__ fw1, const float* __restrict__ fw2,
    const float* __restrict__ pb1, const float* __restrict__ pb2,
    const float* __restrict__ fb1, const float* __restrict__ fb2,
    u16* __restrict__ sb, u16* __restrict__ W1T, u16* __restrict__ W2T,
    float* __restrict__ bias1, float* __restrict__ bias2,
    float* __restrict__ states)
{
    const int N0 = BATCH * 512;      // seq conversion
    const int N1 = 1024 * 512;       // W1T
    const int N2 = 768 * 512;        // W2T
    const int N3 = 1024;             // bias1
    const int N4 = 768;              // bias2
    const int N5 = BATCH * 18 + 4;   // states + loss
    int i = blockIdx.x * 256 + threadIdx.x;
    if (i < N0) { sb[i] = f2bf(seq[i]); return; }
    i -= N0;
    if (i < N1) {
        int n = i >> 9, k = i & 511;
        float v = (n < 512) ? pw1[(size_t)k * 512 + n] : fw1[(size_t)k * 512 + (n - 512)];
        W1T[i] = f2bf(v); return;
    }
    i -= N1;
    if (i < N2) {
        int n = i >> 9, k = i & 511;
        float v = (n < 256) ? pw2[(size_t)k * 256 + n] : fw2[(size_t)k * 512 + (n - 256)];
        W2T[i] = f2bf(v); return;
    }
    i -= N2;
    if (i < N3) { bias1[i] = (i < 512) ? pb1[i] : fb1[i - 512]; return; }
    i -= N3;
    if (i < N4) { bias2[i] = (i < 256) ? pb2[i] : fb2[i - 256]; return; }
    i -= N4;
    if (i < N5) { states[i] = 0.0f; return; }
}

// ---------------------------------------------------------------------------
// bf16 MFMA GEMM: C[M,N](bf16) = act(A[M,K](bf16) @ Bt[N,K]^T + bias)
// 128x128 tile, 4 waves (each a 64x64 quadrant), BK=64, 16x16x32 bf16 MFMA.
// A pointer selected per column tile (A0 if bn < n_split, else A1).
// ---------------------------------------------------------------------------
#define LDP 72  // padded LDS row length (bf16 elems): 64 + 8

__global__ __launch_bounds__(256) void gemm_bf16(
    const u16* __restrict__ A0, const u16* __restrict__ A1, int lda,
    const u16* __restrict__ Bt, const float* __restrict__ bias,
    u16* __restrict__ C, int M, int N, int K, int n_split, int apply_gelu)
{
    __shared__ __align__(16) u16 As[128 * LDP];
    __shared__ __align__(16) u16 Bs[128 * LDP];

    const int bm = blockIdx.x * 128;
    const int bn = blockIdx.y * 128;
    const u16* __restrict__ A = (bn < n_split) ? A0 : A1;

    const int tid = threadIdx.x;
    const int wave = tid >> 6;
    const int lane = tid & 63;
    const int wr = wave >> 1;      // 0..1 : row half
    const int wc = wave & 1;       // 0..1 : col half

    f32x4 acc[4][4];
#pragma unroll
    for (int i = 0; i < 4; ++i)
#pragma unroll
        for (int j = 0; j < 4; ++j) acc[i][j] = (f32x4){0.f, 0.f, 0.f, 0.f};

    for (int k0 = 0; k0 < K; k0 += 64) {
        // stage A tile (128 x 64) and Bt tile (128 x 64): 1024 x 16B chunks each
#pragma unroll
        for (int c = 0; c < 4; ++c) {
            int chunk = tid + c * 256;
            int row = chunk >> 3;
            int col8 = (chunk & 7) << 3;
            uint4 va = *reinterpret_cast<const uint4*>(&A[(size_t)(bm + row) * lda + k0 + col8]);
            *reinterpret_cast<uint4*>(&As[row * LDP + col8]) = va;
            uint4 vb = *reinterpret_cast<const uint4*>(&Bt[(size_t)(bn + row) * K + k0 + col8]);
            *reinterpret_cast<uint4*>(&Bs[row * LDP + col8]) = vb;
        }
        __syncthreads();

#pragma unroll
        for (int ks = 0; ks < 64; ks += 32) {
            int kk = ks + (lane >> 4) * 8;
            bf16x8 af[4], bfr[4];
#pragma unroll
            for (int i = 0; i < 4; ++i)
                af[i] = *reinterpret_cast<const bf16x8*>(&As[(wr * 64 + i * 16 + (lane & 15)) * LDP + kk]);
#pragma unroll
            for (int j = 0; j < 4; ++j)
                bfr[j] = *reinterpret_cast<const bf16x8*>(&Bs[(wc * 64 + j * 16 + (lane & 15)) * LDP + kk]);
#pragma unroll
            for (int i = 0; i < 4; ++i)
#pragma unroll
                for (int j = 0; j < 4; ++j)
                    acc[i][j] = __builtin_amdgcn_mfma_f32_16x16x32_bf16(af[i], bfr[j], acc[i][j], 0, 0, 0);
        }
        __syncthreads();
    }

    // epilogue: D layout col = lane&15, row = (lane>>4)*4 + reg
    const int r4 = (lane >> 4) * 4;
    const int cn = lane & 15;
#pragma unroll
    for (int i = 0; i < 4; ++i) {
#pragma unroll
        for (int j = 0; j < 4; ++j) {
            int gcol = bn + wc * 64 + j * 16 + cn;
            float bsv = bias[gcol];
#pragma unroll
            for (int r = 0; r < 4; ++r) {
                int grow = bm + wr * 64 + i * 16 + r4 + r;
                float v = acc[i][j][r] + bsv;
                if (apply_gelu) v = gelu_exact(v);
                C[(size_t)grow * N + gcol] = f2bf(v);
            }
        }
    }
}

// ---------------------------------------------------------------------------
// step_h1: H1[b, 0:512]  = gelu(Z[b,0:512]   + pres_state@pw1[512:518] + pw1[518+ridx])
//          H1[b,512:1024]= gelu(Z[b,512:1024]+ full_state@fw1[512:524] + fw1[524+ridx])
// ---------------------------------------------------------------------------
__global__ __launch_bounds__(256) void step_h1(
    const u16* __restrict__ Z, const float* __restrict__ pw1, const float* __restrict__ fw1,
    const float* __restrict__ pres_state, const float* __restrict__ full_state,
    const int* __restrict__ perm_idx, int step, u16* __restrict__ H1)
{
    int gid = blockIdx.x * 256 + threadIdx.x;
    int b = gid >> 7;
    int chunk = gid & 127;
    int col0 = chunk << 3;
    int ridx = PERMS_C[perm_idx[b]][step];
    u16x8 z = *reinterpret_cast<const u16x8*>(&Z[(size_t)b * 1024 + col0]);
    u16x8 o;
    if (col0 < 512) {
        float s0[6];
#pragma unroll
        for (int t = 0; t < 6; ++t) s0[t] = pres_state[b * 6 + t];
        const float* oh = &pw1[(size_t)(518 + ridx) * 512 + col0];
#pragma unroll
        for (int e = 0; e < 8; ++e) {
            int j = col0 + e;
            float d = oh[e];
#pragma unroll
            for (int t = 0; t < 6; ++t) d += s0[t] * pw1[(size_t)(512 + t) * 512 + j];
            o[e] = f2bf(gelu_exact(bf2f(z[e]) + d));
        }
    } else {
        int jc = col0 - 512;
        float s0[12];
#pragma unroll
        for (int t = 0; t < 12; ++t) s0[t] = full_state[b * 12 + t];
        const float* oh = &fw1[(size_t)(524 + ridx) * 512 + jc];
#pragma unroll
        for (int e = 0; e < 8; ++e) {
            int j = jc + e;
            float d = oh[e];
#pragma unroll
            for (int t = 0; t < 12; ++t) d += s0[t] * fw1[(size_t)(512 + t) * 512 + j];
            o[e] = f2bf(gelu_exact(bf2f(z[e]) + d));
        }
    }
    *reinterpret_cast<u16x8*>(&H1[(size_t)b * 1024 + col0]) = o;
}

// ---------------------------------------------------------------------------
// step_head: layer-3 matvecs + sigmoid/BCE/clip + state update + loss partials.
// One wave per row (4 rows / 256-thread block).
// H2 row layout: [0:256] = gelu(h2p), [256:768] = gelu(h2f)
// ---------------------------------------------------------------------------
__global__ __launch_bounds__(256) void step_head(
    const u16* __restrict__ H2,
    const float* __restrict__ pw3, const float* __restrict__ pb3,
    const float* __restrict__ fw3, const float* __restrict__ fb3,
    const float* __restrict__ freq, const float* __restrict__ presv,
    const float* __restrict__ enrich,
    const int* __restrict__ round_mask, const int* __restrict__ perm_idx, int step,
    float* __restrict__ pres_state, float* __restrict__ full_state,
    float* __restrict__ loss_acc, float* __restrict__ out)
{
    const int wid = threadIdx.x >> 6;
    const int lane = threadIdx.x & 63;
    const int b = blockIdx.x * 4 + wid;
    const u16* h2 = &H2[(size_t)b * 768];

    float sp = 0.f;
#pragma unroll
    for (int t = 0; t < 4; ++t) {
        int k = lane * 4 + t;
        sp += bf2f(h2[k]) * pw3[k];
    }
    float sf = 0.f, se = 0.f;
#pragma unroll
    for (int t = 0; t < 8; ++t) {
        int k = lane * 8 + t;
        float h = bf2f(h2[256 + k]);
        sf += h * fw3[2 * k];
        se += h * fw3[2 * k + 1];
    }
    for (int off = 32; off > 0; off >>= 1) {
        sp += __shfl_down(sp, off);
        sf += __shfl_down(sf, off);
        se += __shfl_down(se, off);
    }

    __shared__ float part[4][4];
    if (lane == 0) {
        float logit = sp + pb3[0];
        float pf = sf + fb3[0];
        float pe = se + fb3[1];
        int ridx = PERMS_C[perm_idx[b]][step];
        float gt_f = freq[b * 3 + ridx];
        float gt_p = presv[b * 3 + ridx];
        float gt_e = enrich[b * 3 + ridx];
        float m = (float)round_mask[b * 3 + ridx];
        float lf = (pf - gt_f) * (pf - gt_f) * m;
        float bce = (fmaxf(logit, 0.f) - logit * gt_p + log1pf(expf(-fabsf(logit)))) * m;
        float le = (pe - gt_e) * (pe - gt_e) * m;
        bool msk = m > 0.5f;
        float act_f = msk ? fminf(fmaxf(pf, -10.f), 10.f) : gt_f;
        float act_p = msk ? 1.f / (1.f + expf(-logit)) : gt_p;
        float act_e = msk ? fminf(fmaxf(pe, -100.f), 100.f) : gt_e;
        pres_state[b * 6 + ridx * 2 + 0] = act_p;
        pres_state[b * 6 + ridx * 2 + 1] = 1.f;
        full_state[b * 12 + ridx * 4 + 0] = act_f;
        full_state[b * 12 + ridx * 4 + 1] = act_p;
        full_state[b * 12 + ridx * 4 + 2] = act_e;
        full_state[b * 12 + ridx * 4 + 3] = 1.f;
        out[3 + b * 3 + ridx] = act_f;
        out[3 + 3 * BATCH + b * 3 + ridx] = act_p;
        out[3 + 6 * BATCH + b * 3 + ridx] = act_e;
        part[wid][0] = lf; part[wid][1] = bce; part[wid][2] = le; part[wid][3] = m;
    }
    __syncthreads();
    if (threadIdx.x == 0) {
        float a0 = 0.f, a1 = 0.f, a2 = 0.f, a3 = 0.f;
#pragma unroll
        for (int w2 = 0; w2 < 4; ++w2) {
            a0 += part[w2][0]; a1 += part[w2][1]; a2 += part[w2][2]; a3 += part[w2][3];
        }
        atomicAdd(&loss_acc[0], a0);
        atomicAdd(&loss_acc[1], a1);
        atomicAdd(&loss_acc[2], a2);
        atomicAdd(&loss_acc[3], a3);
    }
}

__global__ void finalize_kernel(const float* __restrict__ loss_acc, float* __restrict__ out)
{
    float nm = loss_acc[3] + 1e-8f;
    out[0] = loss_acc[0] / nm;
    out[1] = loss_acc[1] / nm;
    out[2] = loss_acc[2] / nm;
}

// ---------------------------------------------------------------------------
extern "C" void kernel_launch(void* const* d_in, const int* in_sizes, int n_in,
                              void* d_out, int out_size, void* d_ws, size_t ws_size,
                              hipStream_t stream)
{
    const float* seq       = (const float*)d_in[0];
    const float* freq      = (const float*)d_in[1];
    const float* presv     = (const float*)d_in[2];
    const float* enrich    = (const float*)d_in[3];
    const float* pw1       = (const float*)d_in[4];
    const float* pb1       = (const float*)d_in[5];
    const float* pw2       = (const float*)d_in[6];
    const float* pb2       = (const float*)d_in[7];
    const float* pw3       = (const float*)d_in[8];
    const float* pb3       = (const float*)d_in[9];
    const float* fw1       = (const float*)d_in[10];
    const float* fb1       = (const float*)d_in[11];
    const float* fw2       = (const float*)d_in[12];
    const float* fb2       = (const float*)d_in[13];
    const float* fw3       = (const float*)d_in[14];
    const float* fb3       = (const float*)d_in[15];
    const int*   perm_idx  = (const int*)d_in[16];
    const int*   round_mask= (const int*)d_in[17];
    float* out = (float*)d_out;

    char* w = (char*)d_ws;
    u16* sb  = (u16*)w;  w += (size_t)BATCH * 512 * 2;   // 16 MB
    u16* Z   = (u16*)w;  w += (size_t)BATCH * 1024 * 2;  // 32 MB
    u16* H1  = (u16*)w;  w += (size_t)BATCH * 1024 * 2;  // 32 MB
    u16* H2  = (u16*)w;  w += (size_t)BATCH * 768 * 2;   // 24 MB
    u16* W1T = (u16*)w;  w += (size_t)1024 * 512 * 2;
    u16* W2T = (u16*)w;  w += (size_t)768 * 512 * 2;
    float* bias1 = (float*)w; w += 1024 * 4;
    float* bias2 = (float*)w; w += 768 * 4;
    float* states = (float*)w;
    float* pres_state = states;
    float* full_state = states + (size_t)BATCH * 6;
    float* loss_acc   = states + (size_t)BATCH * 18;

    // prep
    {
        const int total = BATCH * 512 + 1024 * 512 + 768 * 512 + 1024 + 768 + (BATCH * 18 + 4);
        int grid = (total + 255) / 256;
        prep_kernel<<<grid, 256, 0, stream>>>(seq, pw1, pw2, fw1, fw2, pb1, pb2, fb1, fb2,
                                              sb, W1T, W2T, bias1, bias2, states);
    }

    // Z = seq @ [pw1[:512] | fw1[:512]] + bias1   (M=16384, N=1024, K=512)
    gemm_bf16<<<dim3(BATCH / 128, 1024 / 128), 256, 0, stream>>>(
        sb, sb, 512, W1T, bias1, Z, BATCH, 1024, 512, 1 << 30, 0);

    for (int s = 0; s < 3; ++s) {
        step_h1<<<BATCH * 128 / 256, 256, 0, stream>>>(
            Z, pw1, fw1, pres_state, full_state, perm_idx, s, H1);

        // H2 = gelu([H1p|H1f] @ [pw2|fw2] + bias2)  (M=16384, N=768, K=512)
        gemm_bf16<<<dim3(BATCH / 128, 768 / 128), 256, 0, stream>>>(
            H1, H1 + 512, 1024, W2T, bias2, H2, BATCH, 768, 512, 256, 1);

        step_head<<<BATCH / 4, 256, 0, stream>>>(
            H2, pw3, pb3, fw3, fb3, freq, presv, enrich,
            round_mask, perm_idx, s, pres_state, full_state, loss_acc, out);
    }

    finalize_kernel<<<1, 1, 0, stream>>>(loss_acc, out);
}

// Round 2
// 997.804 us; speedup vs baseline: 1.7583x; 1.7583x over previous
//
#include <hip/hip_runtime.h>
#include <hip/hip_bf16.h>
#include <math.h>

#define BATCH 16384

typedef unsigned short u16;
typedef short bf16x8 __attribute__((ext_vector_type(8)));
typedef float f32x4 __attribute__((ext_vector_type(4)));
typedef u16 u16x8 __attribute__((ext_vector_type(8)));
typedef u16 u16x4 __attribute__((ext_vector_type(4)));

__constant__ int PERMS_C[6][3] = {{0,1,2},{0,2,1},{1,0,2},{1,2,0},{2,0,1},{2,1,0}};

__device__ inline float bf2f(u16 u) {
    unsigned int x = ((unsigned int)u) << 16;
    float f; __builtin_memcpy(&f, &x, 4); return f;
}
__device__ inline u16 f2bf(float f) {
    __hip_bfloat16 h = __float2bfloat16(f);
    u16 u; __builtin_memcpy(&u, &h, 2); return u;
}
__device__ inline float gelu_exact(float x) {
    return 0.5f * x * (1.0f + erff(x * 0.70710678118654752f));
}

// ---------------------------------------------------------------------------
// prep: convert seq_embed to bf16, build transposed bf16 weight blocks,
// concatenated biases, zero states + loss accumulators.
// ---------------------------------------------------------------------------
__global__ __launch_bounds__(256) void prep_kernel(
    const float* __restrict__ seq,
    const float* __restrict__ pw1, const float* __restrict__ pw2,
    const float* __restrict__ fw1, const float* __restrict__ fw2,
    const float* __restrict__ pb1, const float* __restrict__ pb2,
    const float* __restrict__ fb1, const float* __restrict__ fb2,
    u16* __restrict__ sb, u16* __restrict__ W1T, u16* __restrict__ W2T,
    float* __restrict__ bias1, float* __restrict__ bias2,
    float* __restrict__ states)
{
    const int N0 = BATCH * 512;      // seq conversion
    const int N1 = 1024 * 512;       // W1T
    const int N2 = 768 * 512;        // W2T
    const int N3 = 1024;             // bias1
    const int N4 = 768;              // bias2
    const int N5 = BATCH * 18 + 4;   // states + loss
    int i = blockIdx.x * 256 + threadIdx.x;
    if (i < N0) { sb[i] = f2bf(seq[i]); return; }
    i -= N0;
    if (i < N1) {
        int n = i >> 9, k = i & 511;
        float v = (n < 512) ? pw1[(size_t)k * 512 + n] : fw1[(size_t)k * 512 + (n - 512)];
        W1T[i] = f2bf(v); return;
    }
    i -= N1;
    if (i < N2) {
        int n = i >> 9, k = i & 511;
        float v = (n < 256) ? pw2[(size_t)k * 256 + n] : fw2[(size_t)k * 512 + (n - 256)];
        W2T[i] = f2bf(v); return;
    }
    i -= N2;
    if (i < N3) { bias1[i] = (i < 512) ? pb1[i] : fb1[i - 512]; return; }
    i -= N3;
    if (i < N4) { bias2[i] = (i < 256) ? pb2[i] : fb2[i - 256]; return; }
    i -= N4;
    if (i < N5) { states[i] = 0.0f; return; }
}

// ---------------------------------------------------------------------------
// bf16 MFMA GEMM: C[M,N](bf16) = act(A[M,K](bf16) @ Bt[N,K]^T + bias)
// 128x128 tile, 4 waves (each a 64x64 quadrant), BK=64, 16x16x32 bf16 MFMA.
// A pointer selected per column tile (A0 if bn < n_split, else A1).
// ---------------------------------------------------------------------------
#define LDP 72  // padded LDS row length (bf16 elems): 64 + 8

__global__ __launch_bounds__(256) void gemm_bf16(
    const u16* __restrict__ A0, const u16* __restrict__ A1, int lda,
    const u16* __restrict__ Bt, const float* __restrict__ bias,
    u16* __restrict__ C, int M, int N, int K, int n_split, int apply_gelu)
{
    __shared__ __align__(16) u16 As[128 * LDP];
    __shared__ __align__(16) u16 Bs[128 * LDP];

    const int bm = blockIdx.x * 128;
    const int bn = blockIdx.y * 128;
    const u16* __restrict__ A = (bn < n_split) ? A0 : A1;

    const int tid = threadIdx.x;
    const int wave = tid >> 6;
    const int lane = tid & 63;
    const int wr = wave >> 1;      // 0..1 : row half
    const int wc = wave & 1;       // 0..1 : col half

    f32x4 acc[4][4];
#pragma unroll
    for (int i = 0; i < 4; ++i)
#pragma unroll
        for (int j = 0; j < 4; ++j) acc[i][j] = (f32x4){0.f, 0.f, 0.f, 0.f};

    for (int k0 = 0; k0 < K; k0 += 64) {
        // stage A tile (128 x 64) and Bt tile (128 x 64): 1024 x 16B chunks each
#pragma unroll
        for (int c = 0; c < 4; ++c) {
            int chunk = tid + c * 256;
            int row = chunk >> 3;
            int col8 = (chunk & 7) << 3;
            uint4 va = *reinterpret_cast<const uint4*>(&A[(size_t)(bm + row) * lda + k0 + col8]);
            *reinterpret_cast<uint4*>(&As[row * LDP + col8]) = va;
            uint4 vb = *reinterpret_cast<const uint4*>(&Bt[(size_t)(bn + row) * K + k0 + col8]);
            *reinterpret_cast<uint4*>(&Bs[row * LDP + col8]) = vb;
        }
        __syncthreads();

#pragma unroll
        for (int ks = 0; ks < 64; ks += 32) {
            int kk = ks + (lane >> 4) * 8;
            bf16x8 af[4], bfr[4];
#pragma unroll
            for (int i = 0; i < 4; ++i)
                af[i] = *reinterpret_cast<const bf16x8*>(&As[(wr * 64 + i * 16 + (lane & 15)) * LDP + kk]);
#pragma unroll
            for (int j = 0; j < 4; ++j)
                bfr[j] = *reinterpret_cast<const bf16x8*>(&Bs[(wc * 64 + j * 16 + (lane & 15)) * LDP + kk]);
#pragma unroll
            for (int i = 0; i < 4; ++i)
#pragma unroll
                for (int j = 0; j < 4; ++j)
                    acc[i][j] = __builtin_amdgcn_mfma_f32_16x16x32_bf16(af[i], bfr[j], acc[i][j], 0, 0, 0);
        }
        __syncthreads();
    }

    // epilogue: D layout col = lane&15, row = (lane>>4)*4 + reg
    const int r4 = (lane >> 4) * 4;
    const int cn = lane & 15;
#pragma unroll
    for (int i = 0; i < 4; ++i) {
#pragma unroll
        for (int j = 0; j < 4; ++j) {
            int gcol = bn + wc * 64 + j * 16 + cn;
            float bsv = bias[gcol];
#pragma unroll
            for (int r = 0; r < 4; ++r) {
                int grow = bm + wr * 64 + i * 16 + r4 + r;
                float v = acc[i][j][r] + bsv;
                if (apply_gelu) v = gelu_exact(v);
                C[(size_t)grow * N + gcol] = f2bf(v);
            }
        }
    }
}

// ---------------------------------------------------------------------------
// step_h1 v2: weights-in-registers, row-streaming.
// H1[b, colBase + 0:512] = gelu(Z[b, colBase + col] + state@W + onehot_row)
// Template NSTATE = 6 (pres half) or 12 (full half).
// Each block: 256 threads = 4 row-streams x 64 col-chunks (8 cols each).
// Each block handles 16 rows (4 per thread). Weights (NSTATE+3 rows x 8 cols)
// live in registers, compile-time indexed (no scratch).
// ---------------------------------------------------------------------------
template<int NSTATE>
__global__ __launch_bounds__(256) void step_h1_t(
    const u16* __restrict__ Z, const float* __restrict__ wsrc,
    const float* __restrict__ state, const int* __restrict__ perm_idx, int step,
    u16* __restrict__ H1, int colBase)
{
    constexpr int NR = NSTATE + 3;
    const int tid = threadIdx.x;
    const int c64 = tid & 63;          // column chunk
    const int ws = tid >> 6;           // row stream 0..3
    const int col0 = c64 * 8;

    float w[NR][8];
#pragma unroll
    for (int t = 0; t < NR; ++t) {
        float4 a = *reinterpret_cast<const float4*>(&wsrc[(size_t)t * 512 + col0]);
        float4 b = *reinterpret_cast<const float4*>(&wsrc[(size_t)t * 512 + col0 + 4]);
        w[t][0] = a.x; w[t][1] = a.y; w[t][2] = a.z; w[t][3] = a.w;
        w[t][4] = b.x; w[t][5] = b.y; w[t][6] = b.z; w[t][7] = b.w;
    }

    int row = blockIdx.x * 16 + ws;
#pragma unroll 2
    for (int i = 0; i < 4; ++i, row += 4) {
        const int ridx = PERMS_C[perm_idx[row]][step];
        float s0[NSTATE];
        if constexpr (NSTATE == 6) {
            float2 a = *reinterpret_cast<const float2*>(&state[row * 6]);
            float2 b = *reinterpret_cast<const float2*>(&state[row * 6 + 2]);
            float2 c = *reinterpret_cast<const float2*>(&state[row * 6 + 4]);
            s0[0] = a.x; s0[1] = a.y; s0[2] = b.x; s0[3] = b.y; s0[4] = c.x; s0[5] = c.y;
        } else {
            float4 a = *reinterpret_cast<const float4*>(&state[row * 12]);
            float4 b = *reinterpret_cast<const float4*>(&state[row * 12 + 4]);
            float4 c = *reinterpret_cast<const float4*>(&state[row * 12 + 8]);
            s0[0] = a.x; s0[1] = a.y; s0[2]  = a.z; s0[3]  = a.w;
            s0[4] = b.x; s0[5] = b.y; s0[6]  = b.z; s0[7]  = b.w;
            s0[8] = c.x; s0[9] = c.y; s0[10] = c.z; s0[11] = c.w;
        }
        u16x8 z = *reinterpret_cast<const u16x8*>(&Z[(size_t)row * 1024 + colBase + col0]);
        u16x8 o;
#pragma unroll
        for (int e = 0; e < 8; ++e) {
            float d = (ridx == 0) ? w[NSTATE][e]
                    : ((ridx == 1) ? w[NSTATE + 1][e] : w[NSTATE + 2][e]);
#pragma unroll
            for (int t = 0; t < NSTATE; ++t) d += s0[t] * w[t][e];
            o[e] = f2bf(gelu_exact(bf2f(z[e]) + d));
        }
        *reinterpret_cast<u16x8*>(&H1[(size_t)row * 1024 + colBase + col0]) = o;
    }
}

// ---------------------------------------------------------------------------
// step_head: layer-3 matvecs + sigmoid/BCE/clip + state update + loss partials.
// One wave per row (4 rows / 256-thread block), vectorized H2/weight loads.
// H2 row layout: [0:256] = gelu(h2p), [256:768] = gelu(h2f)
// ---------------------------------------------------------------------------
__global__ __launch_bounds__(256) void step_head(
    const u16* __restrict__ H2,
    const float* __restrict__ pw3, const float* __restrict__ pb3,
    const float* __restrict__ fw3, const float* __restrict__ fb3,
    const float* __restrict__ freq, const float* __restrict__ presv,
    const float* __restrict__ enrich,
    const int* __restrict__ round_mask, const int* __restrict__ perm_idx, int step,
    float* __restrict__ pres_state, float* __restrict__ full_state,
    float* __restrict__ loss_acc, float* __restrict__ out)
{
    const int wid = threadIdx.x >> 6;
    const int lane = threadIdx.x & 63;
    const int b = blockIdx.x * 4 + wid;
    const u16* h2 = &H2[(size_t)b * 768];

    u16x4 hp = *reinterpret_cast<const u16x4*>(&h2[lane * 4]);
    float4 wp = *reinterpret_cast<const float4*>(&pw3[lane * 4]);
    float sp = bf2f(hp[0]) * wp.x + bf2f(hp[1]) * wp.y
             + bf2f(hp[2]) * wp.z + bf2f(hp[3]) * wp.w;

    u16x8 hf = *reinterpret_cast<const u16x8*>(&h2[256 + lane * 8]);
    float4 wa = *reinterpret_cast<const float4*>(&fw3[lane * 16]);
    float4 wb = *reinterpret_cast<const float4*>(&fw3[lane * 16 + 4]);
    float4 wc = *reinterpret_cast<const float4*>(&fw3[lane * 16 + 8]);
    float4 wd = *reinterpret_cast<const float4*>(&fw3[lane * 16 + 12]);
    float h0 = bf2f(hf[0]), h1 = bf2f(hf[1]), h2v = bf2f(hf[2]), h3 = bf2f(hf[3]);
    float h4 = bf2f(hf[4]), h5 = bf2f(hf[5]), h6v = bf2f(hf[6]), h7 = bf2f(hf[7]);
    float sf = h0 * wa.x + h1 * wa.z + h2v * wb.x + h3 * wb.z
             + h4 * wc.x + h5 * wc.z + h6v * wd.x + h7 * wd.z;
    float se = h0 * wa.y + h1 * wa.w + h2v * wb.y + h3 * wb.w
             + h4 * wc.y + h5 * wc.w + h6v * wd.y + h7 * wd.w;

    for (int off = 32; off > 0; off >>= 1) {
        sp += __shfl_down(sp, off);
        sf += __shfl_down(sf, off);
        se += __shfl_down(se, off);
    }

    __shared__ float part[4][4];
    if (lane == 0) {
        float logit = sp + pb3[0];
        float pf = sf + fb3[0];
        float pe = se + fb3[1];
        int ridx = PERMS_C[perm_idx[b]][step];
        float gt_f = freq[b * 3 + ridx];
        float gt_p = presv[b * 3 + ridx];
        float gt_e = enrich[b * 3 + ridx];
        float m = (float)round_mask[b * 3 + ridx];
        float lf = (pf - gt_f) * (pf - gt_f) * m;
        float bce = (fmaxf(logit, 0.f) - logit * gt_p + log1pf(expf(-fabsf(logit)))) * m;
        float le = (pe - gt_e) * (pe - gt_e) * m;
        bool msk = m > 0.5f;
        float act_f = msk ? fminf(fmaxf(pf, -10.f), 10.f) : gt_f;
        float act_p = msk ? 1.f / (1.f + expf(-logit)) : gt_p;
        float act_e = msk ? fminf(fmaxf(pe, -100.f), 100.f) : gt_e;
        pres_state[b * 6 + ridx * 2 + 0] = act_p;
        pres_state[b * 6 + ridx * 2 + 1] = 1.f;
        full_state[b * 12 + ridx * 4 + 0] = act_f;
        full_state[b * 12 + ridx * 4 + 1] = act_p;
        full_state[b * 12 + ridx * 4 + 2] = act_e;
        full_state[b * 12 + ridx * 4 + 3] = 1.f;
        out[3 + b * 3 + ridx] = act_f;
        out[3 + 3 * BATCH + b * 3 + ridx] = act_p;
        out[3 + 6 * BATCH + b * 3 + ridx] = act_e;
        part[wid][0] = lf; part[wid][1] = bce; part[wid][2] = le; part[wid][3] = m;
    }
    __syncthreads();
    if (threadIdx.x == 0) {
        float a0 = 0.f, a1 = 0.f, a2 = 0.f, a3 = 0.f;
#pragma unroll
        for (int w2 = 0; w2 < 4; ++w2) {
            a0 += part[w2][0]; a1 += part[w2][1]; a2 += part[w2][2]; a3 += part[w2][3];
        }
        atomicAdd(&loss_acc[0], a0);
        atomicAdd(&loss_acc[1], a1);
        atomicAdd(&loss_acc[2], a2);
        atomicAdd(&loss_acc[3], a3);
    }
}

__global__ void finalize_kernel(const float* __restrict__ loss_acc, float* __restrict__ out)
{
    float nm = loss_acc[3] + 1e-8f;
    out[0] = loss_acc[0] / nm;
    out[1] = loss_acc[1] / nm;
    out[2] = loss_acc[2] / nm;
}

// ---------------------------------------------------------------------------
extern "C" void kernel_launch(void* const* d_in, const int* in_sizes, int n_in,
                              void* d_out, int out_size, void* d_ws, size_t ws_size,
                              hipStream_t stream)
{
    const float* seq       = (const float*)d_in[0];
    const float* freq      = (const float*)d_in[1];
    const float* presv     = (const float*)d_in[2];
    const float* enrich    = (const float*)d_in[3];
    const float* pw1       = (const float*)d_in[4];
    const float* pb1       = (const float*)d_in[5];
    const float* pw2       = (const float*)d_in[6];
    const float* pb2       = (const float*)d_in[7];
    const float* pw3       = (const float*)d_in[8];
    const float* pb3       = (const float*)d_in[9];
    const float* fw1       = (const float*)d_in[10];
    const float* fb1       = (const float*)d_in[11];
    const float* fw2       = (const float*)d_in[12];
    const float* fb2       = (const float*)d_in[13];
    const float* fw3       = (const float*)d_in[14];
    const float* fb3       = (const float*)d_in[15];
    const int*   perm_idx  = (const int*)d_in[16];
    const int*   round_mask= (const int*)d_in[17];
    float* out = (float*)d_out;

    char* w = (char*)d_ws;
    u16* sb  = (u16*)w;  w += (size_t)BATCH * 512 * 2;   // 16 MB
    u16* Z   = (u16*)w;  w += (size_t)BATCH * 1024 * 2;  // 32 MB
    u16* H1  = (u16*)w;  w += (size_t)BATCH * 1024 * 2;  // 32 MB
    u16* H2  = (u16*)w;  w += (size_t)BATCH * 768 * 2;   // 24 MB
    u16* W1T = (u16*)w;  w += (size_t)1024 * 512 * 2;
    u16* W2T = (u16*)w;  w += (size_t)768 * 512 * 2;
    float* bias1 = (float*)w; w += 1024 * 4;
    float* bias2 = (float*)w; w += 768 * 4;
    float* states = (float*)w;
    float* pres_state = states;
    float* full_state = states + (size_t)BATCH * 6;
    float* loss_acc   = states + (size_t)BATCH * 18;

    // prep
    {
        const int total = BATCH * 512 + 1024 * 512 + 768 * 512 + 1024 + 768 + (BATCH * 18 + 4);
        int grid = (total + 255) / 256;
        prep_kernel<<<grid, 256, 0, stream>>>(seq, pw1, pw2, fw1, fw2, pb1, pb2, fb1, fb2,
                                              sb, W1T, W2T, bias1, bias2, states);
    }

    // Z = seq @ [pw1[:512] | fw1[:512]] + bias1   (M=16384, N=1024, K=512)
    gemm_bf16<<<dim3(BATCH / 128, 1024 / 128), 256, 0, stream>>>(
        sb, sb, 512, W1T, bias1, Z, BATCH, 1024, 512, 1 << 30, 0);

    for (int s = 0; s < 3; ++s) {
        step_h1_t<6><<<BATCH / 16, 256, 0, stream>>>(
            Z, pw1 + (size_t)512 * 512, pres_state, perm_idx, s, H1, 0);
        step_h1_t<12><<<BATCH / 16, 256, 0, stream>>>(
            Z, fw1 + (size_t)512 * 512, full_state, perm_idx, s, H1, 512);

        // H2 = gelu([H1p|H1f] @ [pw2|fw2] + bias2)  (M=16384, N=768, K=512)
        gemm_bf16<<<dim3(BATCH / 128, 768 / 128), 256, 0, stream>>>(
            H1, H1 + 512, 1024, W2T, bias2, H2, BATCH, 768, 512, 256, 1);

        step_head<<<BATCH / 4, 256, 0, stream>>>(
            H2, pw3, pb3, fw3, fb3, freq, presv, enrich,
            round_mask, perm_idx, s, pres_state, full_state, loss_acc, out);
    }

    finalize_kernel<<<1, 1, 0, stream>>>(loss_acc, out);
}

// Round 3
// 380.907 us; speedup vs baseline: 4.6059x; 2.6195x over previous
//
#include <hip/hip_runtime.h>
#include <hip/hip_bf16.h>
#include <math.h>

#define BATCH 16384

typedef unsigned short u16;
typedef short bf16x8 __attribute__((ext_vector_type(8)));
typedef float f32x4 __attribute__((ext_vector_type(4)));
typedef u16 u16x8 __attribute__((ext_vector_type(8)));
typedef u16 u16x4 __attribute__((ext_vector_type(4)));

__constant__ int PERMS_C[6][3] = {{0,1,2},{0,2,1},{1,0,2},{1,2,0},{2,0,1},{2,1,0}};

__device__ inline float bf2f(u16 u) {
    unsigned int x = ((unsigned int)u) << 16;
    float f; __builtin_memcpy(&f, &x, 4); return f;
}
__device__ inline u16 f2bf(float f) {
    __hip_bfloat16 h = __float2bfloat16(f);
    u16 u; __builtin_memcpy(&u, &h, 2); return u;
}
__device__ inline float gelu_exact(float x) {
    return 0.5f * x * (1.0f + erff(x * 0.70710678118654752f));
}

// ---------------------------------------------------------------------------
// prep: convert seq_embed to bf16, build transposed bf16 weight blocks,
// concatenated biases, zero states.
// ---------------------------------------------------------------------------
__global__ __launch_bounds__(256) void prep_kernel(
    const float* __restrict__ seq,
    const float* __restrict__ pw1, const float* __restrict__ pw2,
    const float* __restrict__ fw1, const float* __restrict__ fw2,
    const float* __restrict__ pb1, const float* __restrict__ pb2,
    const float* __restrict__ fb1, const float* __restrict__ fb2,
    u16* __restrict__ sb, u16* __restrict__ W1T, u16* __restrict__ W2T,
    float* __restrict__ bias1, float* __restrict__ bias2,
    float* __restrict__ states)
{
    const int N0 = BATCH * 512;      // seq conversion
    const int N1 = 1024 * 512;       // W1T
    const int N2 = 768 * 512;        // W2T
    const int N3 = 1024;             // bias1
    const int N4 = 768;              // bias2
    const int N5 = BATCH * 18;       // states
    int i = blockIdx.x * 256 + threadIdx.x;
    if (i < N0) { sb[i] = f2bf(seq[i]); return; }
    i -= N0;
    if (i < N1) {
        int n = i >> 9, k = i & 511;
        float v = (n < 512) ? pw1[(size_t)k * 512 + n] : fw1[(size_t)k * 512 + (n - 512)];
        W1T[i] = f2bf(v); return;
    }
    i -= N1;
    if (i < N2) {
        int n = i >> 9, k = i & 511;
        float v = (n < 256) ? pw2[(size_t)k * 256 + n] : fw2[(size_t)k * 512 + (n - 256)];
        W2T[i] = f2bf(v); return;
    }
    i -= N2;
    if (i < N3) { bias1[i] = (i < 512) ? pb1[i] : fb1[i - 512]; return; }
    i -= N3;
    if (i < N4) { bias2[i] = (i < 256) ? pb2[i] : fb2[i - 256]; return; }
    i -= N4;
    if (i < N5) { states[i] = 0.0f; return; }
}

// ---------------------------------------------------------------------------
// bf16 MFMA GEMM: C[M,N](bf16) = act(A[M,K](bf16) @ Bt[N,K]^T + bias)
// 128x128 tile, 4 waves (each a 64x64 quadrant), BK=64, 16x16x32 bf16 MFMA.
// A pointer selected per column tile (A0 if bn < n_split, else A1).
// ---------------------------------------------------------------------------
#define LDP 72  // padded LDS row length (bf16 elems): 64 + 8

__global__ __launch_bounds__(256) void gemm_bf16(
    const u16* __restrict__ A0, const u16* __restrict__ A1, int lda,
    const u16* __restrict__ Bt, const float* __restrict__ bias,
    u16* __restrict__ C, int M, int N, int K, int n_split, int apply_gelu)
{
    __shared__ __align__(16) u16 As[128 * LDP];
    __shared__ __align__(16) u16 Bs[128 * LDP];

    const int bm = blockIdx.x * 128;
    const int bn = blockIdx.y * 128;
    const u16* __restrict__ A = (bn < n_split) ? A0 : A1;

    const int tid = threadIdx.x;
    const int wave = tid >> 6;
    const int lane = tid & 63;
    const int wr = wave >> 1;      // 0..1 : row half
    const int wc = wave & 1;       // 0..1 : col half

    f32x4 acc[4][4];
#pragma unroll
    for (int i = 0; i < 4; ++i)
#pragma unroll
        for (int j = 0; j < 4; ++j) acc[i][j] = (f32x4){0.f, 0.f, 0.f, 0.f};

    for (int k0 = 0; k0 < K; k0 += 64) {
#pragma unroll
        for (int c = 0; c < 4; ++c) {
            int chunk = tid + c * 256;
            int row = chunk >> 3;
            int col8 = (chunk & 7) << 3;
            uint4 va = *reinterpret_cast<const uint4*>(&A[(size_t)(bm + row) * lda + k0 + col8]);
            *reinterpret_cast<uint4*>(&As[row * LDP + col8]) = va;
            uint4 vb = *reinterpret_cast<const uint4*>(&Bt[(size_t)(bn + row) * K + k0 + col8]);
            *reinterpret_cast<uint4*>(&Bs[row * LDP + col8]) = vb;
        }
        __syncthreads();

#pragma unroll
        for (int ks = 0; ks < 64; ks += 32) {
            int kk = ks + (lane >> 4) * 8;
            bf16x8 af[4], bfr[4];
#pragma unroll
            for (int i = 0; i < 4; ++i)
                af[i] = *reinterpret_cast<const bf16x8*>(&As[(wr * 64 + i * 16 + (lane & 15)) * LDP + kk]);
#pragma unroll
            for (int j = 0; j < 4; ++j)
                bfr[j] = *reinterpret_cast<const bf16x8*>(&Bs[(wc * 64 + j * 16 + (lane & 15)) * LDP + kk]);
#pragma unroll
            for (int i = 0; i < 4; ++i)
#pragma unroll
                for (int j = 0; j < 4; ++j)
                    acc[i][j] = __builtin_amdgcn_mfma_f32_16x16x32_bf16(af[i], bfr[j], acc[i][j], 0, 0, 0);
        }
        __syncthreads();
    }

    const int r4 = (lane >> 4) * 4;
    const int cn = lane & 15;
#pragma unroll
    for (int i = 0; i < 4; ++i) {
#pragma unroll
        for (int j = 0; j < 4; ++j) {
            int gcol = bn + wc * 64 + j * 16 + cn;
            float bsv = bias[gcol];
#pragma unroll
            for (int r = 0; r < 4; ++r) {
                int grow = bm + wr * 64 + i * 16 + r4 + r;
                float v = acc[i][j][r] + bsv;
                if (apply_gelu) v = gelu_exact(v);
                C[(size_t)grow * N + gcol] = f2bf(v);
            }
        }
    }
}

// ---------------------------------------------------------------------------
// step_h1: weights-in-registers, row-streaming.
// ---------------------------------------------------------------------------
template<int NSTATE>
__global__ __launch_bounds__(256) void step_h1_t(
    const u16* __restrict__ Z, const float* __restrict__ wsrc,
    const float* __restrict__ state, const int* __restrict__ perm_idx, int step,
    u16* __restrict__ H1, int colBase)
{
    constexpr int NR = NSTATE + 3;
    const int tid = threadIdx.x;
    const int c64 = tid & 63;          // column chunk
    const int ws = tid >> 6;           // row stream 0..3
    const int col0 = c64 * 8;

    float w[NR][8];
#pragma unroll
    for (int t = 0; t < NR; ++t) {
        float4 a = *reinterpret_cast<const float4*>(&wsrc[(size_t)t * 512 + col0]);
        float4 b = *reinterpret_cast<const float4*>(&wsrc[(size_t)t * 512 + col0 + 4]);
        w[t][0] = a.x; w[t][1] = a.y; w[t][2] = a.z; w[t][3] = a.w;
        w[t][4] = b.x; w[t][5] = b.y; w[t][6] = b.z; w[t][7] = b.w;
    }

    int row = blockIdx.x * 16 + ws;
#pragma unroll 2
    for (int i = 0; i < 4; ++i, row += 4) {
        const int ridx = PERMS_C[perm_idx[row]][step];
        float s0[NSTATE];
        if constexpr (NSTATE == 6) {
            float2 a = *reinterpret_cast<const float2*>(&state[row * 6]);
            float2 b = *reinterpret_cast<const float2*>(&state[row * 6 + 2]);
            float2 c = *reinterpret_cast<const float2*>(&state[row * 6 + 4]);
            s0[0] = a.x; s0[1] = a.y; s0[2] = b.x; s0[3] = b.y; s0[4] = c.x; s0[5] = c.y;
        } else {
            float4 a = *reinterpret_cast<const float4*>(&state[row * 12]);
            float4 b = *reinterpret_cast<const float4*>(&state[row * 12 + 4]);
            float4 c = *reinterpret_cast<const float4*>(&state[row * 12 + 8]);
            s0[0] = a.x; s0[1] = a.y; s0[2]  = a.z; s0[3]  = a.w;
            s0[4] = b.x; s0[5] = b.y; s0[6]  = b.z; s0[7]  = b.w;
            s0[8] = c.x; s0[9] = c.y; s0[10] = c.z; s0[11] = c.w;
        }
        u16x8 z = *reinterpret_cast<const u16x8*>(&Z[(size_t)row * 1024 + colBase + col0]);
        u16x8 o;
#pragma unroll
        for (int e = 0; e < 8; ++e) {
            float d = (ridx == 0) ? w[NSTATE][e]
                    : ((ridx == 1) ? w[NSTATE + 1][e] : w[NSTATE + 2][e]);
#pragma unroll
            for (int t = 0; t < NSTATE; ++t) d += s0[t] * w[t][e];
            o[e] = f2bf(gelu_exact(bf2f(z[e]) + d));
        }
        *reinterpret_cast<u16x8*>(&H1[(size_t)row * 1024 + colBase + col0]) = o;
    }
}

// ---------------------------------------------------------------------------
// step_head v3: 16 rows/block, hoisted weights, parallel tails, no atomics.
// Phase A: wave w computes matvecs for rows w*4..w*4+3 -> (logit,pf,pe) to LDS.
// Phase B: lanes 0..15 of wave 0 handle per-row tails in parallel; loss
//          partials wave-reduced and written (non-atomic) to part[block].
// ---------------------------------------------------------------------------
__global__ __launch_bounds__(256) void step_head(
    const u16* __restrict__ H2,
    const float* __restrict__ pw3, const float* __restrict__ pb3,
    const float* __restrict__ fw3, const float* __restrict__ fb3,
    const float* __restrict__ freq, const float* __restrict__ presv,
    const float* __restrict__ enrich,
    const int* __restrict__ round_mask, const int* __restrict__ perm_idx, int step,
    float* __restrict__ pres_state, float* __restrict__ full_state,
    float* __restrict__ part, float* __restrict__ out)
{
    const int wid = threadIdx.x >> 6;
    const int lane = threadIdx.x & 63;
    const int row0 = blockIdx.x * 16;

    __shared__ float lg[16][4];

    // hoisted weights (row-invariant)
    float4 wp = *reinterpret_cast<const float4*>(&pw3[lane * 4]);
    float4 wa = *reinterpret_cast<const float4*>(&fw3[lane * 16]);
    float4 wb = *reinterpret_cast<const float4*>(&fw3[lane * 16 + 4]);
    float4 wc = *reinterpret_cast<const float4*>(&fw3[lane * 16 + 8]);
    float4 wd = *reinterpret_cast<const float4*>(&fw3[lane * 16 + 12]);

#pragma unroll
    for (int i = 0; i < 4; ++i) {
        const int r = wid * 4 + i;
        const int b = row0 + r;
        const u16* h2 = &H2[(size_t)b * 768];

        u16x4 hp = *reinterpret_cast<const u16x4*>(&h2[lane * 4]);
        float sp = bf2f(hp[0]) * wp.x + bf2f(hp[1]) * wp.y
                 + bf2f(hp[2]) * wp.z + bf2f(hp[3]) * wp.w;

        u16x8 hf = *reinterpret_cast<const u16x8*>(&h2[256 + lane * 8]);
        float h0 = bf2f(hf[0]), h1 = bf2f(hf[1]), h2v = bf2f(hf[2]), h3 = bf2f(hf[3]);
        float h4 = bf2f(hf[4]), h5 = bf2f(hf[5]), h6v = bf2f(hf[6]), h7 = bf2f(hf[7]);
        float sf = h0 * wa.x + h1 * wa.z + h2v * wb.x + h3 * wb.z
                 + h4 * wc.x + h5 * wc.z + h6v * wd.x + h7 * wd.z;
        float se = h0 * wa.y + h1 * wa.w + h2v * wb.y + h3 * wb.w
                 + h4 * wc.y + h5 * wc.w + h6v * wd.y + h7 * wd.w;

        for (int off = 32; off > 0; off >>= 1) {
            sp += __shfl_down(sp, off);
            sf += __shfl_down(sf, off);
            se += __shfl_down(se, off);
        }
        if (lane == 0) { lg[r][0] = sp; lg[r][1] = sf; lg[r][2] = se; }
    }
    __syncthreads();

    float lf = 0.f, bce = 0.f, le = 0.f, mm = 0.f;
    if (wid == 0) {
        if (lane < 16) {
            const int b = row0 + lane;
            float logit = lg[lane][0] + pb3[0];
            float pf    = lg[lane][1] + fb3[0];
            float pe    = lg[lane][2] + fb3[1];
            int ridx = PERMS_C[perm_idx[b]][step];
            float gt_f = freq[b * 3 + ridx];
            float gt_p = presv[b * 3 + ridx];
            float gt_e = enrich[b * 3 + ridx];
            float m = (float)round_mask[b * 3 + ridx];
            lf  = (pf - gt_f) * (pf - gt_f) * m;
            bce = (fmaxf(logit, 0.f) - logit * gt_p + log1pf(expf(-fabsf(logit)))) * m;
            le  = (pe - gt_e) * (pe - gt_e) * m;
            mm  = m;
            bool msk = m > 0.5f;
            float act_f = msk ? fminf(fmaxf(pf, -10.f), 10.f) : gt_f;
            float act_p = msk ? 1.f / (1.f + expf(-logit)) : gt_p;
            float act_e = msk ? fminf(fmaxf(pe, -100.f), 100.f) : gt_e;
            pres_state[b * 6 + ridx * 2 + 0] = act_p;
            pres_state[b * 6 + ridx * 2 + 1] = 1.f;
            full_state[b * 12 + ridx * 4 + 0] = act_f;
            full_state[b * 12 + ridx * 4 + 1] = act_p;
            full_state[b * 12 + ridx * 4 + 2] = act_e;
            full_state[b * 12 + ridx * 4 + 3] = 1.f;
            out[3 + b * 3 + ridx] = act_f;
            out[3 + 3 * BATCH + b * 3 + ridx] = act_p;
            out[3 + 6 * BATCH + b * 3 + ridx] = act_e;
        }
        for (int off = 8; off > 0; off >>= 1) {
            lf  += __shfl_down(lf, off);
            bce += __shfl_down(bce, off);
            le  += __shfl_down(le, off);
            mm  += __shfl_down(mm, off);
        }
        if (lane == 0) {
            float4 v; v.x = lf; v.y = bce; v.z = le; v.w = mm;
            *reinterpret_cast<float4*>(&part[blockIdx.x * 4]) = v;
        }
    }
}

#define HEAD_BLOCKS (BATCH / 16)

__global__ __launch_bounds__(256) void finalize_kernel(
    const float* __restrict__ part, float* __restrict__ out)
{
    __shared__ float red[4][4];
    const int nslots = 3 * HEAD_BLOCKS;
    float a0 = 0.f, a1 = 0.f, a2 = 0.f, a3 = 0.f;
    for (int j = threadIdx.x; j < nslots; j += 256) {
        float4 v = *reinterpret_cast<const float4*>(&part[j * 4]);
        a0 += v.x; a1 += v.y; a2 += v.z; a3 += v.w;
    }
    for (int off = 32; off > 0; off >>= 1) {
        a0 += __shfl_down(a0, off);
        a1 += __shfl_down(a1, off);
        a2 += __shfl_down(a2, off);
        a3 += __shfl_down(a3, off);
    }
    const int wid = threadIdx.x >> 6, lane = threadIdx.x & 63;
    if (lane == 0) { red[wid][0] = a0; red[wid][1] = a1; red[wid][2] = a2; red[wid][3] = a3; }
    __syncthreads();
    if (threadIdx.x == 0) {
        float s0 = 0.f, s1 = 0.f, s2 = 0.f, s3 = 0.f;
#pragma unroll
        for (int w2 = 0; w2 < 4; ++w2) {
            s0 += red[w2][0]; s1 += red[w2][1]; s2 += red[w2][2]; s3 += red[w2][3];
        }
        float nm = s3 + 1e-8f;
        out[0] = s0 / nm;
        out[1] = s1 / nm;
        out[2] = s2 / nm;
    }
}

// ---------------------------------------------------------------------------
extern "C" void kernel_launch(void* const* d_in, const int* in_sizes, int n_in,
                              void* d_out, int out_size, void* d_ws, size_t ws_size,
                              hipStream_t stream)
{
    const float* seq       = (const float*)d_in[0];
    const float* freq      = (const float*)d_in[1];
    const float* presv     = (const float*)d_in[2];
    const float* enrich    = (const float*)d_in[3];
    const float* pw1       = (const float*)d_in[4];
    const float* pb1       = (const float*)d_in[5];
    const float* pw2       = (const float*)d_in[6];
    const float* pb2       = (const float*)d_in[7];
    const float* pw3       = (const float*)d_in[8];
    const float* pb3       = (const float*)d_in[9];
    const float* fw1       = (const float*)d_in[10];
    const float* fb1       = (const float*)d_in[11];
    const float* fw2       = (const float*)d_in[12];
    const float* fb2       = (const float*)d_in[13];
    const float* fw3       = (const float*)d_in[14];
    const float* fb3       = (const float*)d_in[15];
    const int*   perm_idx  = (const int*)d_in[16];
    const int*   round_mask= (const int*)d_in[17];
    float* out = (float*)d_out;

    char* w = (char*)d_ws;
    u16* sb  = (u16*)w;  w += (size_t)BATCH * 512 * 2;   // 16 MB
    u16* Z   = (u16*)w;  w += (size_t)BATCH * 1024 * 2;  // 32 MB
    u16* H1  = (u16*)w;  w += (size_t)BATCH * 1024 * 2;  // 32 MB
    u16* H2  = (u16*)w;  w += (size_t)BATCH * 768 * 2;   // 24 MB
    u16* W1T = (u16*)w;  w += (size_t)1024 * 512 * 2;
    u16* W2T = (u16*)w;  w += (size_t)768 * 512 * 2;
    float* bias1 = (float*)w; w += 1024 * 4;
    float* bias2 = (float*)w; w += 768 * 4;
    float* states = (float*)w; w += (size_t)BATCH * 18 * 4;
    float* part   = (float*)w;
    float* pres_state = states;
    float* full_state = states + (size_t)BATCH * 6;

    // prep
    {
        const int total = BATCH * 512 + 1024 * 512 + 768 * 512 + 1024 + 768 + BATCH * 18;
        int grid = (total + 255) / 256;
        prep_kernel<<<grid, 256, 0, stream>>>(seq, pw1, pw2, fw1, fw2, pb1, pb2, fb1, fb2,
                                              sb, W1T, W2T, bias1, bias2, states);
    }

    // Z = seq @ [pw1[:512] | fw1[:512]] + bias1   (M=16384, N=1024, K=512)
    gemm_bf16<<<dim3(BATCH / 128, 1024 / 128), 256, 0, stream>>>(
        sb, sb, 512, W1T, bias1, Z, BATCH, 1024, 512, 1 << 30, 0);

    for (int s = 0; s < 3; ++s) {
        step_h1_t<6><<<BATCH / 16, 256, 0, stream>>>(
            Z, pw1 + (size_t)512 * 512, pres_state, perm_idx, s, H1, 0);
        step_h1_t<12><<<BATCH / 16, 256, 0, stream>>>(
            Z, fw1 + (size_t)512 * 512, full_state, perm_idx, s, H1, 512);

        // H2 = gelu([H1p|H1f] @ [pw2|fw2] + bias2)  (M=16384, N=768, K=512)
        gemm_bf16<<<dim3(BATCH / 128, 768 / 128), 256, 0, stream>>>(
            H1, H1 + 512, 1024, W2T, bias2, H2, BATCH, 768, 512, 256, 1);

        step_head<<<HEAD_BLOCKS, 256, 0, stream>>>(
            H2, pw3, pb3, fw3, fb3, freq, presv, enrich,
            round_mask, perm_idx, s, pres_state, full_state,
            part + (size_t)s * HEAD_BLOCKS * 4, out);
    }

    finalize_kernel<<<1, 256, 0, stream>>>(part, out);
}